// Round 18
// baseline (305.859 us; speedup 1.0000x reference)
//
#include <hip/hip_runtime.h>
#include <hip/hip_bf16.h>
#include <math.h>

// ---------------------------------------------------------------------------
// GNN: rep = attr @ W_inp^T + b
//      2x { x = (segsoftmax-weighted aggr of rep[src] by dst) + rep;
//           rep = LN(gelu(x @ W_a^T + b)) }
//      out = rep @ W_out^T + b_out
// segment_softmax(log a) == a / (ssum + amax*1e-16) -> per-node scalar.
// CSR build with ZERO per-edge global atomics (random 4B atomic RMWs ~ a
// full gather pass -- round-10 lesson):
//   k_bin:   LDS partition-sort of 4096-edge chunks -> tmp(src*64,a0,a1,dst)
//            + tmpd (dst-only 4B mirror so k_deg reads 6.4MB not 25.6MB).
//   k_deg:   (part,range) blocks build private LDS histograms from tmpd.
//   scan1/3b: row_ptr; histg -> per-(part,range) base offsets in place.
//   k_place: (part,range) blocks place via LDS cursors; csr windows XCD-local
//            (part=blockIdx&31 -> all 8 ranges of a part share XCD part&7).
//            128-thr blocks: segment cnt ~128 -> full lane utilization.
// k_aggr: one wave per node (static 8/block), 16-deep gather unroll, fp8
// e4m3 mirror gathers (halves fill traffic; self-term stays bf16; noise
// enters only via /sqrt(32) weighted mean). HW cvt fp8<->f32.
// Node features packed bf16x2; dense layers bf16 MFMA with fused GELU/LN.
// ---------------------------------------------------------------------------

#define WAVE 64
#define NPARTS 32
#define CHUNKE 4096
#define PARTMAX 2048

typedef __attribute__((ext_vector_type(8))) short bf16x8;
typedef __attribute__((ext_vector_type(4))) float f32x4;
typedef __attribute__((ext_vector_type(2))) float f32x2;
union ABu { uint4 u; bf16x8 v; };
union ABh { ushort h[8]; bf16x8 v; };

static __device__ __forceinline__ float bf2f(uint u16) {
    union { uint i; float f; } c;
    c.i = u16 << 16;
    return c.f;
}
static __device__ __forceinline__ uint f2bf(float f) {
    uint x = __float_as_uint(f);
    return (x + 0x7FFFu + ((x >> 16) & 1u)) >> 16;  // RNE
}

// ---- pass 1: chunk-local LDS sort by dst partition (LDS atomics only) ----
__global__ __launch_bounds__(512) void k_bin(const int* __restrict__ src,
                                             const int* __restrict__ dst,
                                             const float* __restrict__ adv,
                                             int E, int PART,
                                             int4* __restrict__ tmp,
                                             int* __restrict__ tmpd,
                                             int* __restrict__ bstart,
                                             int* __restrict__ bcnt) {
    __shared__ int hist[NPARTS], cur[NPARTS], base_[NPARTS];
    __shared__ int4 buf[CHUNKE];
    int c = blockIdx.x;
    int e0 = c * CHUNKE;
    int cnt = min(CHUNKE, E - e0);
    int dreg[CHUNKE / 512];
    int preg[CHUNKE / 512];
    if (threadIdx.x < NPARTS) hist[threadIdx.x] = 0;
    __syncthreads();
#pragma unroll
    for (int i = 0; i < CHUNKE / 512; ++i) {
        int idx = threadIdx.x + i * 512;
        if (idx < cnt) {
            int d = dst[e0 + idx];
            int pt = d / PART;
            dreg[i] = d;
            preg[i] = pt;
            atomicAdd(&hist[pt], 1);
        }
    }
    __syncthreads();
    if (threadIdx.x < 64) {
        int t = threadIdx.x;
        int v = (t < NPARTS) ? hist[t] : 0;
#pragma unroll
        for (int off = 1; off < NPARTS; off <<= 1) {
            int u = __shfl_up(v, off);
            if (t >= off) v += u;
        }
        if (t < NPARTS) {
            base_[t] = v - hist[t];
            cur[t] = v - hist[t];
        }
    }
    __syncthreads();
#pragma unroll
    for (int i = 0; i < CHUNKE / 512; ++i) {
        int idx = threadIdx.x + i * 512;
        if (idx < cnt) {
            int e = e0 + idx;
            int slot = atomicAdd(&cur[preg[i]], 1);
            buf[slot] = make_int4(src[e] * 64, __float_as_int(adv[e]),
                                  __float_as_int(adv[E + e]), dreg[i]);
        }
    }
    __syncthreads();
    for (int i = threadIdx.x; i < cnt; i += 512) {
        int4 v = buf[i];
        tmp[(size_t)e0 + i] = v;
        tmpd[(size_t)e0 + i] = v.w;
    }
    if (threadIdx.x < NPARTS) {
        bstart[c * NPARTS + threadIdx.x] = e0 + base_[threadIdx.x];
        bcnt[c * NPARTS + threadIdx.x] = hist[threadIdx.x];
    }
}

// ---- pass 2: per-(part,range) private LDS histogram from tmpd ----
__global__ __launch_bounds__(128) void k_deg(const int* __restrict__ tmpd,
                                             const int* __restrict__ bstart,
                                             const int* __restrict__ bcnt,
                                             int nchunk, int crange, int PART, int n,
                                             int* __restrict__ histg) {
    __shared__ int h[PARTMAX];
    int part = blockIdx.x & 31, r = blockIdx.x >> 5;
    for (int j = threadIdx.x; j < PART; j += 128) h[j] = 0;
    __syncthreads();
    int c0 = r * crange, c1 = min(c0 + crange, nchunk);
    int lo = part * PART;
    for (int c = c0; c < c1; ++c) {
        int s = bstart[c * NPARTS + part];
        int cnt = bcnt[c * NPARTS + part];
        for (int i = threadIdx.x; i < cnt; i += 128)
            atomicAdd(&h[tmpd[(size_t)s + i] - lo], 1);
    }
    __syncthreads();
    for (int j = threadIdx.x; j < PART; j += 128)
        histg[(size_t)(part * 8 + r) * PART + j] = h[j];
}

// ---- scan: deg = sum_r histg; per-256 block scan ----
__global__ __launch_bounds__(256) void k_scan1(const int* __restrict__ histg,
                                               int PART, int n,
                                               int* __restrict__ excl,
                                               int* __restrict__ bsum) {
    __shared__ int sd[256];
    int t = threadIdx.x, i = blockIdx.x * 256 + t;
    int v = 0;
    if (i < n) {
        int part = i / PART, off = i - part * PART;
#pragma unroll
        for (int r = 0; r < 8; ++r) v += histg[(size_t)(part * 8 + r) * PART + off];
    }
    sd[t] = v;
    __syncthreads();
    for (int off = 1; off < 256; off <<= 1) {
        int u = (t >= off) ? sd[t - off] : 0;
        __syncthreads();
        sd[t] += u;
        __syncthreads();
    }
    if (i < n) excl[i] = sd[t] - v;
    if (t == 255) bsum[blockIdx.x] = sd[255];
}

// ---- row_ptr + histg -> rbase (in place) ----
__global__ __launch_bounds__(256) void k_scan3b(int* __restrict__ histg,
                                                const int* __restrict__ excl,
                                                const int* __restrict__ bsum,
                                                int nbs, int n, int PART,
                                                int* __restrict__ row_ptr) {
    __shared__ int sd[256];
    int t = threadIdx.x;
    int v = (t < nbs) ? bsum[t] : 0;
    sd[t] = v;
    __syncthreads();
    for (int off = 1; off < 256; off <<= 1) {
        int u = (t >= off) ? sd[t - off] : 0;
        __syncthreads();
        sd[t] += u;
        __syncthreads();
    }
    int pref = (blockIdx.x == 0) ? 0 : sd[blockIdx.x - 1];
    int i = blockIdx.x * 256 + t;
    if (i < n) {
        int rp = pref + excl[i];
        row_ptr[i] = rp;
        int part = i / PART, off = i - part * PART;
        int run = rp;
#pragma unroll
        for (int r = 0; r < 8; ++r) {
            size_t idx = (size_t)(part * 8 + r) * PART + off;
            int h = histg[idx];
            histg[idx] = run;   // rbase
            run += h;
        }
        if (i == n - 1) row_ptr[n] = run;
    }
}

// ---- pass 3: placement via block-private LDS cursors (no global atomics) ----
__global__ __launch_bounds__(128) void k_place(const int4* __restrict__ tmp,
                                               const int* __restrict__ bstart,
                                               const int* __restrict__ bcnt,
                                               const int* __restrict__ rbase,
                                               int nchunk, int crange, int PART, int n,
                                               int2* __restrict__ csr0,
                                               int2* __restrict__ csr1) {
    __shared__ int cur[PARTMAX];
    int part = blockIdx.x & 31, r = blockIdx.x >> 5;
    for (int j = threadIdx.x; j < PART; j += 128)
        cur[j] = rbase[(size_t)(part * 8 + r) * PART + j];
    __syncthreads();
    int c0 = r * crange, c1 = min(c0 + crange, nchunk);
    int lo = part * PART;
    for (int c = c0; c < c1; ++c) {
        int s = bstart[c * NPARTS + part];
        int cnt = bcnt[c * NPARTS + part];
        for (int i = threadIdx.x; i < cnt; i += 128) {
            int4 rec = tmp[(size_t)s + i];
            int pos = atomicAdd(&cur[rec.w - lo], 1);
            csr0[pos] = make_int2(rec.x, rec.y);
            csr1[pos] = make_int2(rec.x, rec.z);
        }
    }
}

// ---- aggregation: one wave per node, 16-deep gather unroll ----
// csr.x = src*64; rep8 is ushort-indexed (2 fp8/lane): rep8[src*64 + lane].
__global__ __launch_bounds__(512) void k_aggr(const uint* __restrict__ rep32,
                                              const ushort* __restrict__ rep8,
                                              const int* __restrict__ row_ptr,
                                              const int2* __restrict__ csr,
                                              uint* __restrict__ xout, int n) {
    int wave = threadIdx.x >> 6, lane = threadIdx.x & 63;
    int node = blockIdx.x * 8 + wave;
    if (node >= n) return;
    int s0 = row_ptr[node], s1 = row_ptr[node + 1];
    float accx = 0.f, accy = 0.f, ssum = 0.f, amax = 0.f;
    int s = s0;
    for (; s + 16 <= s1; s += 16) {
        int2 cc[16];
        ushort rr[16];
#pragma unroll
        for (int k = 0; k < 16; ++k) cc[k] = csr[s + k];
#pragma unroll
        for (int k = 0; k < 16; ++k) rr[k] = rep8[(size_t)(uint)cc[k].x + lane];
#pragma unroll
        for (int k = 0; k < 16; ++k) {
            float a = __int_as_float(cc[k].y);
            ssum += a;
            amax = fmaxf(amax, a);
            f32x2 v = __builtin_amdgcn_cvt_pk_f32_fp8((int)rr[k], false);
            accx = fmaf(a, v.x, accx);
            accy = fmaf(a, v.y, accy);
        }
    }
    for (; s + 4 <= s1; s += 4) {
        int2 cc[4];
        ushort rr[4];
#pragma unroll
        for (int k = 0; k < 4; ++k) cc[k] = csr[s + k];
#pragma unroll
        for (int k = 0; k < 4; ++k) rr[k] = rep8[(size_t)(uint)cc[k].x + lane];
#pragma unroll
        for (int k = 0; k < 4; ++k) {
            float a = __int_as_float(cc[k].y);
            ssum += a;
            amax = fmaxf(amax, a);
            f32x2 v = __builtin_amdgcn_cvt_pk_f32_fp8((int)rr[k], false);
            accx = fmaf(a, v.x, accx);
            accy = fmaf(a, v.y, accy);
        }
    }
    for (; s < s1; ++s) {
        int2 c = csr[s];
        float a = __int_as_float(c.y);
        ushort r = rep8[(size_t)(uint)c.x + lane];
        ssum += a;
        amax = fmaxf(amax, a);
        f32x2 v = __builtin_amdgcn_cvt_pk_f32_fp8((int)r, false);
        accx = fmaf(a, v.x, accx);
        accy = fmaf(a, v.y, accy);
    }
    float inv = (s1 > s0) ? 1.f / (ssum + amax * 1e-16f) : 0.f;
    uint m = rep32[(size_t)node * 64 + lane];
    float ox = fmaf(accx, inv, bf2f(m & 0xffffu));
    float oy = fmaf(accy, inv, bf2f(m >> 16));
    xout[(size_t)node * 64 + lane] = f2bf(ox) | (f2bf(oy) << 16);
}

// ============================ dense MFMA kernels ============================
// 512 threads = 8 waves; wave handles 32 nodes (2 row-tiles of 16).
#define WROW 136  // shorts per LDS W row (128 + 8 pad -> 2-way banks = free)

// ---- MLP: rep(bf16 + fp8 mirror) = LN(gelu(x(bf16) @ W^T + b)) ----
__global__ __launch_bounds__(512) void k_mlp(const uint* __restrict__ x32,
                                             const float* __restrict__ W,
                                             const float* __restrict__ b,
                                             const float* __restrict__ lw,
                                             const float* __restrict__ lb,
                                             uint* __restrict__ out32,
                                             ushort* __restrict__ out8, int n) {
    __shared__ ushort Wbf[128 * WROW];
    uint* wd = (uint*)Wbf;
    for (int idx = threadIdx.x; idx < 128 * 64; idx += 512) {
        int row = idx >> 6, d = idx & 63;
        float2 w2 = *(const float2*)&W[row * 128 + d * 2];
        wd[row * (WROW / 2) + d] = f2bf(w2.x) | (f2bf(w2.y) << 16);
    }
    __syncthreads();
    int wv = threadIdx.x >> 6, l = threadIdx.x & 63;
    int c = l & 15, q = l >> 4;
    int base = blockIdx.x * 256 + wv * 32;
    int r0 = min(base + c, n - 1);
    int r1 = min(base + 16 + c, n - 1);

    f32x4 acc[2][8];
#pragma unroll
    for (int rt = 0; rt < 2; ++rt)
#pragma unroll
        for (int ct = 0; ct < 8; ++ct) acc[rt][ct] = (f32x4){0.f, 0.f, 0.f, 0.f};

#pragma unroll
    for (int kb = 0; kb < 4; ++kb) {
        ABu a0, a1;
        a0.u = *(const uint4*)&x32[(size_t)r0 * 64 + kb * 16 + q * 4];
        a1.u = *(const uint4*)&x32[(size_t)r1 * 64 + kb * 16 + q * 4];
#pragma unroll
        for (int ct = 0; ct < 8; ++ct) {
            bf16x8 bf = *(const bf16x8*)&Wbf[(ct * 16 + c) * WROW + kb * 32 + q * 8];
            acc[0][ct] = __builtin_amdgcn_mfma_f32_16x16x32_bf16(a0.v, bf, acc[0][ct], 0, 0, 0);
            acc[1][ct] = __builtin_amdgcn_mfma_f32_16x16x32_bf16(a1.v, bf, acc[1][ct], 0, 0, 0);
        }
    }

    float bias[8], lwv[8], lbv[8];
#pragma unroll
    for (int ct = 0; ct < 8; ++ct) {
        bias[ct] = b[ct * 16 + c];
        lwv[ct] = lw[ct * 16 + c];
        lbv[ct] = lb[ct * 16 + c];
    }

#pragma unroll
    for (int rt = 0; rt < 2; ++rt) {
#pragma unroll
        for (int ct = 0; ct < 8; ++ct)
#pragma unroll
            for (int i = 0; i < 4; ++i) {
                float h = acc[rt][ct][i] + bias[ct];
                acc[rt][ct][i] = 0.5f * h * (1.f + erff(h * 0.70710678118654752f));
            }
        float mu[4], rstd[4];
#pragma unroll
        for (int i = 0; i < 4; ++i) {
            float s = 0.f;
#pragma unroll
            for (int ct = 0; ct < 8; ++ct) s += acc[rt][ct][i];
            s += __shfl_xor(s, 1);
            s += __shfl_xor(s, 2);
            s += __shfl_xor(s, 4);
            s += __shfl_xor(s, 8);
            mu[i] = s * (1.f / 128.f);
        }
#pragma unroll
        for (int i = 0; i < 4; ++i) {
            float v = 0.f;
#pragma unroll
            for (int ct = 0; ct < 8; ++ct) {
                float d = acc[rt][ct][i] - mu[i];
                v += d * d;
            }
            v += __shfl_xor(v, 1);
            v += __shfl_xor(v, 2);
            v += __shfl_xor(v, 4);
            v += __shfl_xor(v, 8);
            rstd[i] = rsqrtf(v * (1.f / 128.f) + 1e-5f);
        }
#pragma unroll
        for (int ct = 0; ct < 8; ++ct)
#pragma unroll
            for (int i = 0; i < 4; ++i) {
                float o = (acc[rt][ct][i] - mu[i]) * rstd[i] * lwv[ct] + lbv[ct];
                float p = __shfl_xor(o, 1);
                uint dw = (c & 1) ? (f2bf(p) | (f2bf(o) << 16))
                                  : (f2bf(o) | (f2bf(p) << 16));
                int R = base + rt * 16 + q * 4 + i;
                if (R < n && (c & 1) == 0) {
                    out32[(size_t)R * 64 + ct * 8 + (c >> 1)] = dw;
                    uint pk = (uint)__builtin_amdgcn_cvt_pk_fp8_f32(o, p, 0, false);
                    out8[(size_t)R * 64 + ct * 8 + (c >> 1)] = (ushort)pk;
                }
            }
    }
}

// ---- input projection: rep(bf16 + fp8 mirror) = attr(f32) @ W^T + b ----
__global__ __launch_bounds__(512) void k_input(const float* __restrict__ attr,
                                               const float* __restrict__ W,
                                               const float* __restrict__ b,
                                               uint* __restrict__ out32,
                                               ushort* __restrict__ out8, int n) {
    __shared__ ushort Wbf[128 * WROW];
    uint* wd = (uint*)Wbf;
    for (int idx = threadIdx.x; idx < 128 * 64; idx += 512) {
        int row = idx >> 6, d = idx & 63;
        float2 w2 = *(const float2*)&W[row * 128 + d * 2];
        wd[row * (WROW / 2) + d] = f2bf(w2.x) | (f2bf(w2.y) << 16);
    }
    __syncthreads();
    int wv = threadIdx.x >> 6, l = threadIdx.x & 63;
    int c = l & 15, q = l >> 4;
    int base = blockIdx.x * 256 + wv * 32;
    int r0 = min(base + c, n - 1);
    int r1 = min(base + 16 + c, n - 1);

    f32x4 acc[2][8];
#pragma unroll
    for (int rt = 0; rt < 2; ++rt)
#pragma unroll
        for (int ct = 0; ct < 8; ++ct) acc[rt][ct] = (f32x4){0.f, 0.f, 0.f, 0.f};

#pragma unroll
    for (int kb = 0; kb < 4; ++kb) {
        ABh a0, a1;
        float4 f0 = *(const float4*)&attr[(size_t)r0 * 128 + kb * 32 + q * 8];
        float4 f1 = *(const float4*)&attr[(size_t)r0 * 128 + kb * 32 + q * 8 + 4];
        a0.h[0] = f2bf(f0.x); a0.h[1] = f2bf(f0.y); a0.h[2] = f2bf(f0.z); a0.h[3] = f2bf(f0.w);
        a0.h[4] = f2bf(f1.x); a0.h[5] = f2bf(f1.y); a0.h[6] = f2bf(f1.z); a0.h[7] = f2bf(f1.w);
        float4 g0 = *(const float4*)&attr[(size_t)r1 * 128 + kb * 32 + q * 8];
        float4 g1 = *(const float4*)&attr[(size_t)r1 * 128 + kb * 32 + q * 8 + 4];
        a1.h[0] = f2bf(g0.x); a1.h[1] = f2bf(g0.y); a1.h[2] = f2bf(g0.z); a1.h[3] = f2bf(g0.w);
        a1.h[4] = f2bf(g1.x); a1.h[5] = f2bf(g1.y); a1.h[6] = f2bf(g1.z); a1.h[7] = f2bf(g1.w);
#pragma unroll
        for (int ct = 0; ct < 8; ++ct) {
            bf16x8 bf = *(const bf16x8*)&Wbf[(ct * 16 + c) * WROW + kb * 32 + q * 8];
            acc[0][ct] = __builtin_amdgcn_mfma_f32_16x16x32_bf16(a0.v, bf, acc[0][ct], 0, 0, 0);
            acc[1][ct] = __builtin_amdgcn_mfma_f32_16x16x32_bf16(a1.v, bf, acc[1][ct], 0, 0, 0);
        }
    }
    float bias[8];
#pragma unroll
    for (int ct = 0; ct < 8; ++ct) bias[ct] = b[ct * 16 + c];
#pragma unroll
    for (int rt = 0; rt < 2; ++rt)
#pragma unroll
        for (int ct = 0; ct < 8; ++ct)
#pragma unroll
            for (int i = 0; i < 4; ++i) {
                float o = acc[rt][ct][i] + bias[ct];
                float p = __shfl_xor(o, 1);
                uint dw = (c & 1) ? (f2bf(p) | (f2bf(o) << 16))
                                  : (f2bf(o) | (f2bf(p) << 16));
                int R = base + rt * 16 + q * 4 + i;
                if (R < n && (c & 1) == 0) {
                    out32[(size_t)R * 64 + ct * 8 + (c >> 1)] = dw;
                    uint pk = (uint)__builtin_amdgcn_cvt_pk_fp8_f32(o, p, 0, false);
                    out8[(size_t)R * 64 + ct * 8 + (c >> 1)] = (ushort)pk;
                }
            }
}

// ---- output projection: out(f32) = rep(bf16) @ W_out^T + b_out (64 outs) ----
__global__ __launch_bounds__(512) void k_out(const uint* __restrict__ rep32,
                                             const float* __restrict__ W,
                                             const float* __restrict__ b,
                                             float* __restrict__ out, int n) {
    __shared__ ushort Wbf[64 * WROW];
    uint* wd = (uint*)Wbf;
    for (int idx = threadIdx.x; idx < 64 * 64; idx += 512) {
        int row = idx >> 6, d = idx & 63;
        float2 w2 = *(const float2*)&W[row * 128 + d * 2];
        wd[row * (WROW / 2) + d] = f2bf(w2.x) | (f2bf(w2.y) << 16);
    }
    __syncthreads();
    int wv = threadIdx.x >> 6, l = threadIdx.x & 63;
    int c = l & 15, q = l >> 4;
    int base = blockIdx.x * 256 + wv * 32;
    int r0 = min(base + c, n - 1);
    int r1 = min(base + 16 + c, n - 1);

    f32x4 acc[2][4];
#pragma unroll
    for (int rt = 0; rt < 2; ++rt)
#pragma unroll
        for (int ct = 0; ct < 4; ++ct) acc[rt][ct] = (f32x4){0.f, 0.f, 0.f, 0.f};

#pragma unroll
    for (int kb = 0; kb < 4; ++kb) {
        ABu a0, a1;
        a0.u = *(const uint4*)&rep32[(size_t)r0 * 64 + kb * 16 + q * 4];
        a1.u = *(const uint4*)&rep32[(size_t)r1 * 64 + kb * 16 + q * 4];
#pragma unroll
        for (int ct = 0; ct < 4; ++ct) {
            bf16x8 bf = *(const bf16x8*)&Wbf[(ct * 16 + c) * WROW + kb * 32 + q * 8];
            acc[0][ct] = __builtin_amdgcn_mfma_f32_16x16x32_bf16(a0.v, bf, acc[0][ct], 0, 0, 0);
            acc[1][ct] = __builtin_amdgcn_mfma_f32_16x16x32_bf16(a1.v, bf, acc[1][ct], 0, 0, 0);
        }
    }
    float bias[4];
#pragma unroll
    for (int ct = 0; ct < 4; ++ct) bias[ct] = b[ct * 16 + c];
#pragma unroll
    for (int rt = 0; rt < 2; ++rt)
#pragma unroll
        for (int ct = 0; ct < 4; ++ct)
#pragma unroll
            for (int i = 0; i < 4; ++i) {
                int R = base + rt * 16 + q * 4 + i;
                if (R < n) out[(size_t)R * 64 + ct * 16 + c] = acc[rt][ct][i] + bias[ct];
            }
}

extern "C" void kernel_launch(void* const* d_in, const int* in_sizes, int n_in,
                              void* d_out, int out_size, void* d_ws, size_t ws_size,
                              hipStream_t stream) {
    const float* node_attr = (const float*)d_in[0];
    const int* ei = (const int*)d_in[1];
    // d_in[2] = batch_idx (unused)
    const float* adv = (const float*)d_in[3];
    const float* W_inp = (const float*)d_in[4];
    const float* b_inp = (const float*)d_in[5];
    const float* W_a = (const float*)d_in[6];
    const float* b_a = (const float*)d_in[7];
    const float* ln_w = (const float*)d_in[8];
    const float* ln_b = (const float*)d_in[9];
    const float* W_out = (const float*)d_in[10];
    const float* b_out = (const float*)d_in[11];

    const int n = in_sizes[0] / 128;
    const int E = in_sizes[1] / 2;
    const int nchunk = (E + CHUNKE - 1) / CHUNKE;
    const int PART = (n + NPARTS - 1) / NPARTS;  // <= PARTMAX for n <= 65536
    const int crange = (nchunk + 7) / 8;

    // workspace: csr0,csr1 (E int2) | tmp (E int4; A,B overlay after k_place)
    // | tmpd (E int) | histg 32*8*PART | excl n | row_ptr n+1 | bsum 256 |
    // bstart,bcnt | A8 (n*64 ushort fp8 mirror)
    int2* csr0 = (int2*)d_ws;
    int2* csr1 = csr0 + E;
    int4* tmp = (int4*)(csr1 + E);
    uint* A = (uint*)tmp;      // overlays tmp (dead after k_place)
    uint* B = A + (size_t)n * 64;
    int* tmpd = (int*)(tmp + E);                  // E
    int* histg = tmpd + E;                        // 32*8*PART
    int* excl = histg + (size_t)NPARTS * 8 * PART;
    int* row_ptr = excl + n;                      // n+1
    int* bsum = row_ptr + n + 1;                  // 256
    int* bstart = bsum + 256;                     // nchunk*NPARTS
    int* bcnt = bstart + (size_t)nchunk * NPARTS;
    ushort* A8 = (ushort*)(bcnt + (size_t)nchunk * NPARTS);  // n*64 ushort

    const int* src = ei;
    const int* dst = ei + E;

    int nbs = (n + 255) / 256;  // n <= 65536
    k_bin<<<nchunk, 512, 0, stream>>>(src, dst, adv, E, PART, tmp, tmpd, bstart, bcnt);
    k_deg<<<256, 128, 0, stream>>>(tmpd, bstart, bcnt, nchunk, crange, PART, n, histg);
    k_scan1<<<nbs, 256, 0, stream>>>(histg, PART, n, excl, bsum);
    k_scan3b<<<nbs, 256, 0, stream>>>(histg, excl, bsum, nbs, n, PART, row_ptr);
    k_place<<<256, 128, 0, stream>>>(tmp, bstart, bcnt, histg, nchunk, crange,
                                     PART, n, csr0, csr1);

    int nbd = (n + 255) / 256;  // dense kernels: 256 nodes/block
    int nb8 = (n + 7) / 8;
    k_input<<<nbd, 512, 0, stream>>>(node_attr, W_inp, b_inp, A, A8, n);

    // layer 0: B = aggr(A, A8); A,A8 = mlp(B)
    k_aggr<<<nb8, 512, 0, stream>>>(A, A8, row_ptr, csr0, B, n);
    k_mlp<<<nbd, 512, 0, stream>>>(B, W_a, b_a, ln_w, ln_b, A, A8, n);
    // layer 1: B = aggr(A, A8); A,A8 = mlp(B)
    k_aggr<<<nb8, 512, 0, stream>>>(A, A8, row_ptr, csr1, B, n);
    k_mlp<<<nbd, 512, 0, stream>>>(B, W_a + 128 * 128, b_a + 128,
                                   ln_w + 128, ln_b + 128, A, A8, n);

    k_out<<<nbd, 512, 0, stream>>>(A, W_out, b_out, (float*)d_out, n);
}

// Round 19
// 274.979 us; speedup vs baseline: 1.1123x; 1.1123x over previous
//
#include <hip/hip_runtime.h>
#include <hip/hip_bf16.h>
#include <math.h>

// ---------------------------------------------------------------------------
// GNN: rep = attr @ W_inp^T + b
//      2x { x = (segsoftmax-weighted aggr of rep[src] by dst) + rep;
//           rep = LN(gelu(x @ W_a^T + b)) }
//      out = rep @ W_out^T + b_out
// segment_softmax(log a) == a / (ssum + amax*1e-16) -> per-node scalar.
// CSR build with ZERO per-edge global atomics (random 4B atomic RMWs ~ a
// full gather pass -- round-10 lesson):
//   k_bin:   LDS partition-sort of 4096-edge chunks -> tmp(src*64,a0,a1,dst).
//   k_deg:   (part,range) blocks build private LDS histograms (256 thr;
//            round-18 lesson: 128-thr + dst-mirror regressed 30us).
//   scan1/3b: row_ptr; histg -> per-(part,range) base offsets in place.
//   k_place: (part,range) blocks place via LDS cursors; csr windows XCD-local.
// k_aggr: one wave per node (static 8/block), 16-deep gather unroll, fp8
// e4m3 mirror gathers (halves fill traffic; self-term stays bf16; noise
// enters only via /sqrt(32) weighted mean). HW cvt fp8<->f32.
// Node features packed bf16x2; dense layers bf16 MFMA with fused GELU/LN.
// ---------------------------------------------------------------------------

#define WAVE 64
#define NPARTS 32
#define CHUNKE 4096
#define PARTMAX 2048

typedef __attribute__((ext_vector_type(8))) short bf16x8;
typedef __attribute__((ext_vector_type(4))) float f32x4;
typedef __attribute__((ext_vector_type(2))) float f32x2;
union ABu { uint4 u; bf16x8 v; };
union ABh { ushort h[8]; bf16x8 v; };

static __device__ __forceinline__ float bf2f(uint u16) {
    union { uint i; float f; } c;
    c.i = u16 << 16;
    return c.f;
}
static __device__ __forceinline__ uint f2bf(float f) {
    uint x = __float_as_uint(f);
    return (x + 0x7FFFu + ((x >> 16) & 1u)) >> 16;  // RNE
}

// ---- pass 1: chunk-local LDS sort by dst partition (LDS atomics only) ----
__global__ __launch_bounds__(512) void k_bin(const int* __restrict__ src,
                                             const int* __restrict__ dst,
                                             const float* __restrict__ adv,
                                             int E, int PART,
                                             int4* __restrict__ tmp,
                                             int* __restrict__ bstart,
                                             int* __restrict__ bcnt) {
    __shared__ int hist[NPARTS], cur[NPARTS], base_[NPARTS];
    __shared__ int4 buf[CHUNKE];
    int c = blockIdx.x;
    int e0 = c * CHUNKE;
    int cnt = min(CHUNKE, E - e0);
    int dreg[CHUNKE / 512];
    int preg[CHUNKE / 512];
    if (threadIdx.x < NPARTS) hist[threadIdx.x] = 0;
    __syncthreads();
#pragma unroll
    for (int i = 0; i < CHUNKE / 512; ++i) {
        int idx = threadIdx.x + i * 512;
        if (idx < cnt) {
            int d = dst[e0 + idx];
            int pt = d / PART;
            dreg[i] = d;
            preg[i] = pt;
            atomicAdd(&hist[pt], 1);
        }
    }
    __syncthreads();
    if (threadIdx.x < 64) {
        int t = threadIdx.x;
        int v = (t < NPARTS) ? hist[t] : 0;
#pragma unroll
        for (int off = 1; off < NPARTS; off <<= 1) {
            int u = __shfl_up(v, off);
            if (t >= off) v += u;
        }
        if (t < NPARTS) {
            base_[t] = v - hist[t];
            cur[t] = v - hist[t];
        }
    }
    __syncthreads();
#pragma unroll
    for (int i = 0; i < CHUNKE / 512; ++i) {
        int idx = threadIdx.x + i * 512;
        if (idx < cnt) {
            int e = e0 + idx;
            int slot = atomicAdd(&cur[preg[i]], 1);
            buf[slot] = make_int4(src[e] * 64, __float_as_int(adv[e]),
                                  __float_as_int(adv[E + e]), dreg[i]);
        }
    }
    __syncthreads();
    for (int i = threadIdx.x; i < cnt; i += 512) tmp[(size_t)e0 + i] = buf[i];
    if (threadIdx.x < NPARTS) {
        bstart[c * NPARTS + threadIdx.x] = e0 + base_[threadIdx.x];
        bcnt[c * NPARTS + threadIdx.x] = hist[threadIdx.x];
    }
}

// ---- pass 2: per-(part,range) private LDS histogram -> histg ----
__global__ __launch_bounds__(256) void k_deg(const int4* __restrict__ tmp,
                                             const int* __restrict__ bstart,
                                             const int* __restrict__ bcnt,
                                             int nchunk, int crange, int PART, int n,
                                             int* __restrict__ histg) {
    __shared__ int h[PARTMAX];
    int part = blockIdx.x & 31, r = blockIdx.x >> 5;
    for (int j = threadIdx.x; j < PART; j += 256) h[j] = 0;
    __syncthreads();
    int c0 = r * crange, c1 = min(c0 + crange, nchunk);
    int lo = part * PART;
    for (int c = c0; c < c1; ++c) {
        int s = bstart[c * NPARTS + part];
        int cnt = bcnt[c * NPARTS + part];
        for (int i = threadIdx.x; i < cnt; i += 256)
            atomicAdd(&h[tmp[(size_t)s + i].w - lo], 1);
    }
    __syncthreads();
    for (int j = threadIdx.x; j < PART; j += 256)
        histg[(size_t)(part * 8 + r) * PART + j] = h[j];
}

// ---- scan: deg = sum_r histg; per-256 block scan ----
__global__ __launch_bounds__(256) void k_scan1(const int* __restrict__ histg,
                                               int PART, int n,
                                               int* __restrict__ excl,
                                               int* __restrict__ bsum) {
    __shared__ int sd[256];
    int t = threadIdx.x, i = blockIdx.x * 256 + t;
    int v = 0;
    if (i < n) {
        int part = i / PART, off = i - part * PART;
#pragma unroll
        for (int r = 0; r < 8; ++r) v += histg[(size_t)(part * 8 + r) * PART + off];
    }
    sd[t] = v;
    __syncthreads();
    for (int off = 1; off < 256; off <<= 1) {
        int u = (t >= off) ? sd[t - off] : 0;
        __syncthreads();
        sd[t] += u;
        __syncthreads();
    }
    if (i < n) excl[i] = sd[t] - v;
    if (t == 255) bsum[blockIdx.x] = sd[255];
}

// ---- row_ptr + histg -> rbase (in place) ----
__global__ __launch_bounds__(256) void k_scan3b(int* __restrict__ histg,
                                                const int* __restrict__ excl,
                                                const int* __restrict__ bsum,
                                                int nbs, int n, int PART,
                                                int* __restrict__ row_ptr) {
    __shared__ int sd[256];
    int t = threadIdx.x;
    int v = (t < nbs) ? bsum[t] : 0;
    sd[t] = v;
    __syncthreads();
    for (int off = 1; off < 256; off <<= 1) {
        int u = (t >= off) ? sd[t - off] : 0;
        __syncthreads();
        sd[t] += u;
        __syncthreads();
    }
    int pref = (blockIdx.x == 0) ? 0 : sd[blockIdx.x - 1];
    int i = blockIdx.x * 256 + t;
    if (i < n) {
        int rp = pref + excl[i];
        row_ptr[i] = rp;
        int part = i / PART, off = i - part * PART;
        int run = rp;
#pragma unroll
        for (int r = 0; r < 8; ++r) {
            size_t idx = (size_t)(part * 8 + r) * PART + off;
            int h = histg[idx];
            histg[idx] = run;   // rbase
            run += h;
        }
        if (i == n - 1) row_ptr[n] = run;
    }
}

// ---- pass 3: placement via block-private LDS cursors (no global atomics) ----
__global__ __launch_bounds__(256) void k_place(const int4* __restrict__ tmp,
                                               const int* __restrict__ bstart,
                                               const int* __restrict__ bcnt,
                                               const int* __restrict__ rbase,
                                               int nchunk, int crange, int PART, int n,
                                               int2* __restrict__ csr0,
                                               int2* __restrict__ csr1) {
    __shared__ int cur[PARTMAX];
    int part = blockIdx.x & 31, r = blockIdx.x >> 5;
    for (int j = threadIdx.x; j < PART; j += 256)
        cur[j] = rbase[(size_t)(part * 8 + r) * PART + j];
    __syncthreads();
    int c0 = r * crange, c1 = min(c0 + crange, nchunk);
    int lo = part * PART;
    for (int c = c0; c < c1; ++c) {
        int s = bstart[c * NPARTS + part];
        int cnt = bcnt[c * NPARTS + part];
        for (int i = threadIdx.x; i < cnt; i += 256) {
            int4 rec = tmp[(size_t)s + i];
            int pos = atomicAdd(&cur[rec.w - lo], 1);
            csr0[pos] = make_int2(rec.x, rec.y);
            csr1[pos] = make_int2(rec.x, rec.z);
        }
    }
}

// ---- aggregation: one wave per node, 16-deep gather unroll ----
// csr.x = src*64; rep8 is ushort-indexed (2 fp8/lane): rep8[src*64 + lane].
// Gathers decode fp8 via HW cvt; self-term reads bf16 rep32 (exact).
__global__ __launch_bounds__(512) void k_aggr(const uint* __restrict__ rep32,
                                              const ushort* __restrict__ rep8,
                                              const int* __restrict__ row_ptr,
                                              const int2* __restrict__ csr,
                                              uint* __restrict__ xout, int n) {
    int wave = threadIdx.x >> 6, lane = threadIdx.x & 63;
    int node = blockIdx.x * 8 + wave;
    if (node >= n) return;
    int s0 = row_ptr[node], s1 = row_ptr[node + 1];
    float accx = 0.f, accy = 0.f, ssum = 0.f, amax = 0.f;
    int s = s0;
    for (; s + 16 <= s1; s += 16) {
        int2 cc[16];
        ushort rr[16];
#pragma unroll
        for (int k = 0; k < 16; ++k) cc[k] = csr[s + k];
#pragma unroll
        for (int k = 0; k < 16; ++k) rr[k] = rep8[(size_t)(uint)cc[k].x + lane];
#pragma unroll
        for (int k = 0; k < 16; ++k) {
            float a = __int_as_float(cc[k].y);
            ssum += a;
            amax = fmaxf(amax, a);
            f32x2 v = __builtin_amdgcn_cvt_pk_f32_fp8((int)rr[k], false);
            accx = fmaf(a, v.x, accx);
            accy = fmaf(a, v.y, accy);
        }
    }
    for (; s + 4 <= s1; s += 4) {
        int2 cc[4];
        ushort rr[4];
#pragma unroll
        for (int k = 0; k < 4; ++k) cc[k] = csr[s + k];
#pragma unroll
        for (int k = 0; k < 4; ++k) rr[k] = rep8[(size_t)(uint)cc[k].x + lane];
#pragma unroll
        for (int k = 0; k < 4; ++k) {
            float a = __int_as_float(cc[k].y);
            ssum += a;
            amax = fmaxf(amax, a);
            f32x2 v = __builtin_amdgcn_cvt_pk_f32_fp8((int)rr[k], false);
            accx = fmaf(a, v.x, accx);
            accy = fmaf(a, v.y, accy);
        }
    }
    for (; s < s1; ++s) {
        int2 c = csr[s];
        float a = __int_as_float(c.y);
        ushort r = rep8[(size_t)(uint)c.x + lane];
        ssum += a;
        amax = fmaxf(amax, a);
        f32x2 v = __builtin_amdgcn_cvt_pk_f32_fp8((int)r, false);
        accx = fmaf(a, v.x, accx);
        accy = fmaf(a, v.y, accy);
    }
    float inv = (s1 > s0) ? 1.f / (ssum + amax * 1e-16f) : 0.f;
    uint m = rep32[(size_t)node * 64 + lane];
    float ox = fmaf(accx, inv, bf2f(m & 0xffffu));
    float oy = fmaf(accy, inv, bf2f(m >> 16));
    xout[(size_t)node * 64 + lane] = f2bf(ox) | (f2bf(oy) << 16);
}

// ============================ dense MFMA kernels ============================
// 512 threads = 8 waves; wave handles 32 nodes (2 row-tiles of 16).
#define WROW 136  // shorts per LDS W row (128 + 8 pad -> 2-way banks = free)

// ---- MLP: rep(bf16 + fp8 mirror) = LN(gelu(x(bf16) @ W^T + b)) ----
__global__ __launch_bounds__(512) void k_mlp(const uint* __restrict__ x32,
                                             const float* __restrict__ W,
                                             const float* __restrict__ b,
                                             const float* __restrict__ lw,
                                             const float* __restrict__ lb,
                                             uint* __restrict__ out32,
                                             ushort* __restrict__ out8, int n) {
    __shared__ ushort Wbf[128 * WROW];
    uint* wd = (uint*)Wbf;
    for (int idx = threadIdx.x; idx < 128 * 64; idx += 512) {
        int row = idx >> 6, d = idx & 63;
        float2 w2 = *(const float2*)&W[row * 128 + d * 2];
        wd[row * (WROW / 2) + d] = f2bf(w2.x) | (f2bf(w2.y) << 16);
    }
    __syncthreads();
    int wv = threadIdx.x >> 6, l = threadIdx.x & 63;
    int c = l & 15, q = l >> 4;
    int base = blockIdx.x * 256 + wv * 32;
    int r0 = min(base + c, n - 1);
    int r1 = min(base + 16 + c, n - 1);

    f32x4 acc[2][8];
#pragma unroll
    for (int rt = 0; rt < 2; ++rt)
#pragma unroll
        for (int ct = 0; ct < 8; ++ct) acc[rt][ct] = (f32x4){0.f, 0.f, 0.f, 0.f};

#pragma unroll
    for (int kb = 0; kb < 4; ++kb) {
        ABu a0, a1;
        a0.u = *(const uint4*)&x32[(size_t)r0 * 64 + kb * 16 + q * 4];
        a1.u = *(const uint4*)&x32[(size_t)r1 * 64 + kb * 16 + q * 4];
#pragma unroll
        for (int ct = 0; ct < 8; ++ct) {
            bf16x8 bf = *(const bf16x8*)&Wbf[(ct * 16 + c) * WROW + kb * 32 + q * 8];
            acc[0][ct] = __builtin_amdgcn_mfma_f32_16x16x32_bf16(a0.v, bf, acc[0][ct], 0, 0, 0);
            acc[1][ct] = __builtin_amdgcn_mfma_f32_16x16x32_bf16(a1.v, bf, acc[1][ct], 0, 0, 0);
        }
    }

    float bias[8], lwv[8], lbv[8];
#pragma unroll
    for (int ct = 0; ct < 8; ++ct) {
        bias[ct] = b[ct * 16 + c];
        lwv[ct] = lw[ct * 16 + c];
        lbv[ct] = lb[ct * 16 + c];
    }

#pragma unroll
    for (int rt = 0; rt < 2; ++rt) {
#pragma unroll
        for (int ct = 0; ct < 8; ++ct)
#pragma unroll
            for (int i = 0; i < 4; ++i) {
                float h = acc[rt][ct][i] + bias[ct];
                acc[rt][ct][i] = 0.5f * h * (1.f + erff(h * 0.70710678118654752f));
            }
        float mu[4], rstd[4];
#pragma unroll
        for (int i = 0; i < 4; ++i) {
            float s = 0.f;
#pragma unroll
            for (int ct = 0; ct < 8; ++ct) s += acc[rt][ct][i];
            s += __shfl_xor(s, 1);
            s += __shfl_xor(s, 2);
            s += __shfl_xor(s, 4);
            s += __shfl_xor(s, 8);
            mu[i] = s * (1.f / 128.f);
        }
#pragma unroll
        for (int i = 0; i < 4; ++i) {
            float v = 0.f;
#pragma unroll
            for (int ct = 0; ct < 8; ++ct) {
                float d = acc[rt][ct][i] - mu[i];
                v += d * d;
            }
            v += __shfl_xor(v, 1);
            v += __shfl_xor(v, 2);
            v += __shfl_xor(v, 4);
            v += __shfl_xor(v, 8);
            rstd[i] = rsqrtf(v * (1.f / 128.f) + 1e-5f);
        }
#pragma unroll
        for (int ct = 0; ct < 8; ++ct)
#pragma unroll
            for (int i = 0; i < 4; ++i) {
                float o = (acc[rt][ct][i] - mu[i]) * rstd[i] * lwv[ct] + lbv[ct];
                float p = __shfl_xor(o, 1);
                uint dw = (c & 1) ? (f2bf(p) | (f2bf(o) << 16))
                                  : (f2bf(o) | (f2bf(p) << 16));
                int R = base + rt * 16 + q * 4 + i;
                if (R < n && (c & 1) == 0) {
                    out32[(size_t)R * 64 + ct * 8 + (c >> 1)] = dw;
                    uint pk = (uint)__builtin_amdgcn_cvt_pk_fp8_f32(o, p, 0, false);
                    out8[(size_t)R * 64 + ct * 8 + (c >> 1)] = (ushort)pk;
                }
            }
    }
}

// ---- input projection: rep(bf16 + fp8 mirror) = attr(f32) @ W^T + b ----
__global__ __launch_bounds__(512) void k_input(const float* __restrict__ attr,
                                               const float* __restrict__ W,
                                               const float* __restrict__ b,
                                               uint* __restrict__ out32,
                                               ushort* __restrict__ out8, int n) {
    __shared__ ushort Wbf[128 * WROW];
    uint* wd = (uint*)Wbf;
    for (int idx = threadIdx.x; idx < 128 * 64; idx += 512) {
        int row = idx >> 6, d = idx & 63;
        float2 w2 = *(const float2*)&W[row * 128 + d * 2];
        wd[row * (WROW / 2) + d] = f2bf(w2.x) | (f2bf(w2.y) << 16);
    }
    __syncthreads();
    int wv = threadIdx.x >> 6, l = threadIdx.x & 63;
    int c = l & 15, q = l >> 4;
    int base = blockIdx.x * 256 + wv * 32;
    int r0 = min(base + c, n - 1);
    int r1 = min(base + 16 + c, n - 1);

    f32x4 acc[2][8];
#pragma unroll
    for (int rt = 0; rt < 2; ++rt)
#pragma unroll
        for (int ct = 0; ct < 8; ++ct) acc[rt][ct] = (f32x4){0.f, 0.f, 0.f, 0.f};

#pragma unroll
    for (int kb = 0; kb < 4; ++kb) {
        ABh a0, a1;
        float4 f0 = *(const float4*)&attr[(size_t)r0 * 128 + kb * 32 + q * 8];
        float4 f1 = *(const float4*)&attr[(size_t)r0 * 128 + kb * 32 + q * 8 + 4];
        a0.h[0] = f2bf(f0.x); a0.h[1] = f2bf(f0.y); a0.h[2] = f2bf(f0.z); a0.h[3] = f2bf(f0.w);
        a0.h[4] = f2bf(f1.x); a0.h[5] = f2bf(f1.y); a0.h[6] = f2bf(f1.z); a0.h[7] = f2bf(f1.w);
        float4 g0 = *(const float4*)&attr[(size_t)r1 * 128 + kb * 32 + q * 8];
        float4 g1 = *(const float4*)&attr[(size_t)r1 * 128 + kb * 32 + q * 8 + 4];
        a1.h[0] = f2bf(g0.x); a1.h[1] = f2bf(g0.y); a1.h[2] = f2bf(g0.z); a1.h[3] = f2bf(g0.w);
        a1.h[4] = f2bf(g1.x); a1.h[5] = f2bf(g1.y); a1.h[6] = f2bf(g1.z); a1.h[7] = f2bf(g1.w);
#pragma unroll
        for (int ct = 0; ct < 8; ++ct) {
            bf16x8 bf = *(const bf16x8*)&Wbf[(ct * 16 + c) * WROW + kb * 32 + q * 8];
            acc[0][ct] = __builtin_amdgcn_mfma_f32_16x16x32_bf16(a0.v, bf, acc[0][ct], 0, 0, 0);
            acc[1][ct] = __builtin_amdgcn_mfma_f32_16x16x32_bf16(a1.v, bf, acc[1][ct], 0, 0, 0);
        }
    }
    float bias[8];
#pragma unroll
    for (int ct = 0; ct < 8; ++ct) bias[ct] = b[ct * 16 + c];
#pragma unroll
    for (int rt = 0; rt < 2; ++rt)
#pragma unroll
        for (int ct = 0; ct < 8; ++ct)
#pragma unroll
            for (int i = 0; i < 4; ++i) {
                float o = acc[rt][ct][i] + bias[ct];
                float p = __shfl_xor(o, 1);
                uint dw = (c & 1) ? (f2bf(p) | (f2bf(o) << 16))
                                  : (f2bf(o) | (f2bf(p) << 16));
                int R = base + rt * 16 + q * 4 + i;
                if (R < n && (c & 1) == 0) {
                    out32[(size_t)R * 64 + ct * 8 + (c >> 1)] = dw;
                    uint pk = (uint)__builtin_amdgcn_cvt_pk_fp8_f32(o, p, 0, false);
                    out8[(size_t)R * 64 + ct * 8 + (c >> 1)] = (ushort)pk;
                }
            }
}

// ---- output projection: out(f32) = rep(bf16) @ W_out^T + b_out (64 outs) ----
__global__ __launch_bounds__(512) void k_out(const uint* __restrict__ rep32,
                                             const float* __restrict__ W,
                                             const float* __restrict__ b,
                                             float* __restrict__ out, int n) {
    __shared__ ushort Wbf[64 * WROW];
    uint* wd = (uint*)Wbf;
    for (int idx = threadIdx.x; idx < 64 * 64; idx += 512) {
        int row = idx >> 6, d = idx & 63;
        float2 w2 = *(const float2*)&W[row * 128 + d * 2];
        wd[row * (WROW / 2) + d] = f2bf(w2.x) | (f2bf(w2.y) << 16);
    }
    __syncthreads();
    int wv = threadIdx.x >> 6, l = threadIdx.x & 63;
    int c = l & 15, q = l >> 4;
    int base = blockIdx.x * 256 + wv * 32;
    int r0 = min(base + c, n - 1);
    int r1 = min(base + 16 + c, n - 1);

    f32x4 acc[2][4];
#pragma unroll
    for (int rt = 0; rt < 2; ++rt)
#pragma unroll
        for (int ct = 0; ct < 4; ++ct) acc[rt][ct] = (f32x4){0.f, 0.f, 0.f, 0.f};

#pragma unroll
    for (int kb = 0; kb < 4; ++kb) {
        ABu a0, a1;
        a0.u = *(const uint4*)&rep32[(size_t)r0 * 64 + kb * 16 + q * 4];
        a1.u = *(const uint4*)&rep32[(size_t)r1 * 64 + kb * 16 + q * 4];
#pragma unroll
        for (int ct = 0; ct < 4; ++ct) {
            bf16x8 bf = *(const bf16x8*)&Wbf[(ct * 16 + c) * WROW + kb * 32 + q * 8];
            acc[0][ct] = __builtin_amdgcn_mfma_f32_16x16x32_bf16(a0.v, bf, acc[0][ct], 0, 0, 0);
            acc[1][ct] = __builtin_amdgcn_mfma_f32_16x16x32_bf16(a1.v, bf, acc[1][ct], 0, 0, 0);
        }
    }
    float bias[4];
#pragma unroll
    for (int ct = 0; ct < 4; ++ct) bias[ct] = b[ct * 16 + c];
#pragma unroll
    for (int rt = 0; rt < 2; ++rt)
#pragma unroll
        for (int ct = 0; ct < 4; ++ct)
#pragma unroll
            for (int i = 0; i < 4; ++i) {
                int R = base + rt * 16 + q * 4 + i;
                if (R < n) out[(size_t)R * 64 + ct * 16 + c] = acc[rt][ct][i] + bias[ct];
            }
}

extern "C" void kernel_launch(void* const* d_in, const int* in_sizes, int n_in,
                              void* d_out, int out_size, void* d_ws, size_t ws_size,
                              hipStream_t stream) {
    const float* node_attr = (const float*)d_in[0];
    const int* ei = (const int*)d_in[1];
    // d_in[2] = batch_idx (unused)
    const float* adv = (const float*)d_in[3];
    const float* W_inp = (const float*)d_in[4];
    const float* b_inp = (const float*)d_in[5];
    const float* W_a = (const float*)d_in[6];
    const float* b_a = (const float*)d_in[7];
    const float* ln_w = (const float*)d_in[8];
    const float* ln_b = (const float*)d_in[9];
    const float* W_out = (const float*)d_in[10];
    const float* b_out = (const float*)d_in[11];

    const int n = in_sizes[0] / 128;
    const int E = in_sizes[1] / 2;
    const int nchunk = (E + CHUNKE - 1) / CHUNKE;
    const int PART = (n + NPARTS - 1) / NPARTS;  // <= PARTMAX for n <= 65536
    const int crange = (nchunk + 7) / 8;

    // workspace: csr0,csr1 (E int2) | tmp (E int4; A,B overlay after k_place)
    // | histg 32*8*PART | excl n | row_ptr n+1 | bsum 256 | bstart,bcnt |
    // A8 (n*64 ushort fp8 mirror)
    int2* csr0 = (int2*)d_ws;
    int2* csr1 = csr0 + E;
    int4* tmp = (int4*)(csr1 + E);
    uint* A = (uint*)tmp;      // overlays tmp (dead after k_place)
    uint* B = A + (size_t)n * 64;
    int* histg = (int*)(tmp + E);                 // 32*8*PART
    int* excl = histg + (size_t)NPARTS * 8 * PART;
    int* row_ptr = excl + n;                      // n+1
    int* bsum = row_ptr + n + 1;                  // 256
    int* bstart = bsum + 256;                     // nchunk*NPARTS
    int* bcnt = bstart + (size_t)nchunk * NPARTS;
    ushort* A8 = (ushort*)(bcnt + (size_t)nchunk * NPARTS);  // n*64 ushort

    const int* src = ei;
    const int* dst = ei + E;

    int nbs = (n + 255) / 256;  // n <= 65536
    k_bin<<<nchunk, 512, 0, stream>>>(src, dst, adv, E, PART, tmp, bstart, bcnt);
    k_deg<<<256, 256, 0, stream>>>(tmp, bstart, bcnt, nchunk, crange, PART, n, histg);
    k_scan1<<<nbs, 256, 0, stream>>>(histg, PART, n, excl, bsum);
    k_scan3b<<<nbs, 256, 0, stream>>>(histg, excl, bsum, nbs, n, PART, row_ptr);
    k_place<<<256, 256, 0, stream>>>(tmp, bstart, bcnt, histg, nchunk, crange,
                                     PART, n, csr0, csr1);

    int nbd = (n + 255) / 256;  // dense kernels: 256 nodes/block
    int nb8 = (n + 7) / 8;
    k_input<<<nbd, 512, 0, stream>>>(node_attr, W_inp, b_inp, A, A8, n);

    // layer 0: B = aggr(A, A8); A,A8 = mlp(B)
    k_aggr<<<nb8, 512, 0, stream>>>(A, A8, row_ptr, csr0, B, n);
    k_mlp<<<nbd, 512, 0, stream>>>(B, W_a, b_a, ln_w, ln_b, A, A8, n);
    // layer 1: B = aggr(A, A8); A,A8 = mlp(B)
    k_aggr<<<nb8, 512, 0, stream>>>(A, A8, row_ptr, csr1, B, n);
    k_mlp<<<nbd, 512, 0, stream>>>(B, W_a + 128 * 128, b_a + 128,
                                   ln_w + 128, ln_b + 128, A, A8, n);

    k_out<<<nbd, 512, 0, stream>>>(A, W_out, b_out, (float*)d_out, n);
}